// Round 9
// baseline (331.283 us; speedup 1.0000x reference)
//
#include <hip/hip_runtime.h>

#define BATCH 16384
#define NUM   512
#define CONS  512
#define ROWS  8                     // rows per wave/block
#define ZOFF  (NUM*16)              // zeros scratch (neg dummy), 8192 = 0x2000
#define OOFF  (NUM*16 + 16)         // ones scratch (pos dummy), 8208 = 0x2010
#define LDSB  (NUM*16 + 32)         // 8224 B
#define NPAD  (CONS + 4)
#define RSTR  96                    // record words per constraint

typedef _Float16 h2 __attribute__((ext_vector_type(2)));
static __device__ __forceinline__ h2 u2h(unsigned u){ return __builtin_bit_cast(h2,u); }
static __device__ __forceinline__ unsigned h2u(h2 h){ return __builtin_bit_cast(unsigned,h); }
static __device__ __forceinline__ h2 hmax2(h2 a,h2 b){ return __builtin_elementwise_max(a,b); }
static __device__ __forceinline__ h2 hmin2(h2 a,h2 b){ return __builtin_elementwise_min(a,b); }
template<int C>
static __device__ __forceinline__ h2 rormax(h2 x) {
  unsigned v = (unsigned)__builtin_amdgcn_mov_dpp((int)h2u(x), C, 0xF, 0xF, true);
  return hmax2(x, u2h(v));
}
static __device__ __forceinline__ h2 swizmax(h2 x) {    // xor 16 (within 32)
  unsigned v = (unsigned)__builtin_amdgcn_ds_swizzle((int)h2u(x), 0x401F);
  return hmax2(x, u2h(v));
}
static __device__ __forceinline__ h2 bpermax(h2 x, int bpa) {  // xor 32
  unsigned v = (unsigned)__builtin_amdgcn_ds_bpermute(bpa, (int)h2u(x));
  return hmax2(x, u2h(v));
}

// record (RSTR words per c):
// [0..63] per-g quads at [g*4]: {N01, N23, P01, P23} packed u16 offset pairs
//   (quad q word lo = slot(2q sect), hi = slot(2q+1 sect); sects = s/16)
// [64] = ho | fl<<16 ; [65..72] exN ; [73..80] exP ; rest pad.
// fl: 0 sign |1 N1 |2 P1 |3 N2 |4 P2 |5 PR1 |6 PR2 |7-10 exN |11-14 exP |15 SKIP
__global__ __launch_bounds__(64) void prep_kernel(
    const float* __restrict__ pos, const float* __restrict__ neg,
    const int* __restrict__ head_atom, const int* __restrict__ head_sign,
    unsigned* __restrict__ ents) {
  int c = blockIdx.x, lane = threadIdx.x;
  unsigned* rec = ents + (size_t)c * RSTR;
  if (c >= CONS) {
    for (int t = lane; t < RSTR; t += 64) {
      unsigned v;
      if (t < 64) v = ((t & 3) < 2) ? 0x20002000u : 0x20102010u;
      else if (t == 64) v = (unsigned)ZOFF | (0x8000u << 16);   // SKIP
      else if (t < 73) v = ZOFF;
      else if (t < 81) v = OOFF;
      else v = 0;
      rec[t] = v;
    }
    return;
  }
  __shared__ unsigned short LN[96], LP[96];
  __shared__ unsigned short slotN[64], slotP[64];
  __shared__ unsigned char usedN[64], usedP[64];
  __shared__ unsigned short spill[16][8];
  __shared__ int spn[16];
  __shared__ unsigned short exN[8], exP[8];
  __shared__ int exn, exp_;
  slotN[lane] = ZOFF; slotP[lane] = OOFF;
  usedN[lane] = 0;    usedP[lane] = 0;
  if (lane < 8) { exN[lane] = ZOFF; exP[lane] = OOFF; }
  if (lane < 16) spn[lane] = 0;
  __syncthreads();

  int hp1 = (c >= 1) ? head_atom[c-1] : -1;
  int hp2 = (c >= 2) ? head_atom[c-2] : -1;
  int nN = 0, nP = 0;
  bool fN1=false, fP1=false, fN2=false, fP2=false;
  for (int k = 0; k < NUM/64; ++k) {
    int a = k*64 + lane;
    bool ln = neg[(size_t)c*NUM + a] != 0.f;
    bool lp = pos[(size_t)c*NUM + a] != 0.f;
    bool n1 = ln && (a == hp1), n2 = ln && (a == hp2);
    bool p1 = lp && (a == hp1), p2 = lp && (a == hp2);
    fN1 |= (__ballot(n1) != 0ull); fN2 |= (__ballot(n2) != 0ull);
    fP1 |= (__ballot(p1) != 0ull); fP2 |= (__ballot(p2) != 0ull);
    bool kn = ln && !n1 && !n2;
    bool kp = lp && !p1 && !p2;
    unsigned long long mn = __ballot(kn), mp = __ballot(kp);
    unsigned long long lt = (1ull << lane) - 1ull;
    int rn = nN + (int)__popcll(mn & lt);
    int rp = nP + (int)__popcll(mp & lt);
    if (kn && rn < 96) LN[rn] = (unsigned short)a;
    if (kp && rp < 96) LP[rp] = (unsigned short)a;
    nN += (int)__popcll(mn);
    nP += (int)__popcll(mp);
  }
  __syncthreads();
  // residue dealing: slot s = rr*8 + (a&7)
  if (lane < 16) {
    int r = lane & 7;
    bool isP = lane >= 8;
    const unsigned short* L = isP ? LP : LN;
    int n = isP ? nP : nN; if (n > 96) n = 96;
    unsigned short* slot = isP ? slotP : slotN;
    unsigned char* used = isP ? usedP : usedN;
    int rr = 0;
    for (int t = 0; t < n; ++t) {
      int a = L[t];
      if ((a & 7) == r) {
        if (rr < 8) { int s = rr*8 + r; slot[s] = (unsigned short)(a*16); used[s] = 1; }
        else if (rr < 16) spill[lane][rr-8] = (unsigned short)(a*16);
        ++rr;
      }
    }
    spn[lane] = rr > 8 ? (rr > 16 ? 8 : rr - 8) : 0;
  }
  __syncthreads();
  if (lane < 2) {                       // spill placement into free slots (rare-ish)
    bool isP = lane == 1;
    unsigned short* slot = isP ? slotP : slotN;
    unsigned char* used = isP ? usedP : usedN;
    unsigned short* exb = isP ? exP : exN;
    int base = isP ? 8 : 0;
    int e = 0, scan = 0;
    for (int r = 0; r < 8; ++r) {
      int ns = spn[base + r];
      for (int k = 0; k < ns; ++k) {
        unsigned short v = spill[base + r][k];
        while (scan < 64 && used[scan]) ++scan;
        if (scan < 64) { slot[scan] = v; used[scan] = 1; }
        else if (e < 8) exb[e++] = v;
      }
    }
    if (isP) exp_ = e; else exn = e;
  }
  __syncthreads();

  int hc = head_atom[c];
  unsigned fl = 0;
  if (head_sign[c]) fl |= 1u;
  if (fN1) fl |= 2u;  if (fP1) fl |= 4u;
  if (fN2) fl |= 8u;  if (fP2) fl |= 16u;
  if (hc == hp1) fl |= 32u; else if (hc == hp2) fl |= 64u;
  fl |= ((unsigned)exn << 7) | ((unsigned)exp_ << 11);
  unsigned ho = (unsigned)hc * 16u;
  for (int t = lane; t < RSTR; t += 64) {
    unsigned v;
    if (t < 64) {
      int gg = t >> 2, q = t & 3;
      if (q == 0)      v = (unsigned)slotN[gg]    | ((unsigned)slotN[16+gg] << 16);
      else if (q == 1) v = (unsigned)slotN[32+gg] | ((unsigned)slotN[48+gg] << 16);
      else if (q == 2) v = (unsigned)slotP[gg]    | ((unsigned)slotP[16+gg] << 16);
      else             v = (unsigned)slotP[32+gg] | ((unsigned)slotP[48+gg] << 16);
    } else if (t == 64) v = ho | (fl << 16);
    else if (t < 73) v = exN[t - 65];
    else if (t < 81) v = exP[t - 73];
    else v = 0;
    rec[t] = v;
  }
}

struct RDv { h2 n0,n1,n2,n3,p0,p1,p2,p3,pv; unsigned m; };
struct ST  { h2 braw, prevraw; unsigned ho, fl; };

static __device__ __forceinline__ void issue_reads(uint4 q, unsigned m,
                                                   const char* Pb, unsigned pr4, RDv& R) {
  R.n0 = *(const h2*)(Pb + ((q.x & 0xFFFFu) + pr4));
  R.n1 = *(const h2*)(Pb + ((q.x >> 16)     + pr4));
  R.n2 = *(const h2*)(Pb + ((q.y & 0xFFFFu) + pr4));
  R.n3 = *(const h2*)(Pb + ((q.y >> 16)     + pr4));
  R.p0 = *(const h2*)(Pb + ((q.z & 0xFFFFu) + pr4));
  R.p1 = *(const h2*)(Pb + ((q.z >> 16)     + pr4));
  R.p2 = *(const h2*)(Pb + ((q.w & 0xFFFFu) + pr4));
  R.p3 = *(const h2*)(Pb + ((q.w >> 16)     + pr4));
  R.pv = *(const h2*)(Pb + ((m & 0xFFFFu) + pr4));
  R.m = m;
}
static __device__ __forceinline__ void combine(const RDv& R, const unsigned* ents,
                                               int c, const char* Pb, unsigned pr4,
                                               int bpa, ST& S) {
  h2 aN = hmax2(hmax2(R.n0, R.n1), hmax2(R.n2, R.n3));
  h2 aP = hmin2(hmin2(R.p0, R.p1), hmin2(R.p2, R.p3));
  unsigned fl = R.m >> 16;
  if (fl & 0x7F80u) {                        // rare extras tail (uniform)
    const unsigned* rec = ents + (size_t)c * RSTR;
    unsigned xn = (fl >> 7) & 15u, xp = (fl >> 11) & 15u;
    for (unsigned j = 0; j < xn; ++j) aN = hmax2(aN, *(const h2*)(Pb + (rec[65+j] + pr4)));
    for (unsigned j = 0; j < xp; ++j) aP = hmin2(aP, *(const h2*)(Pb + (rec[73+j] + pr4)));
  }
  const h2 one2 = {(_Float16)1.f, (_Float16)1.f};
  h2 bp = hmax2(aN, one2 - aP);               // >= 0 by construction
  bp = rormax<0x124>(bp);                     // xor-class 4 (row_ror:4)
  bp = rormax<0x128>(bp);                     // xor-class 8 (row_ror:8)
  bp = swizmax(bp);                           // xor 16
  bp = bpermax(bp, bpa);                      // xor 32
  S.braw = bp; S.prevraw = R.pv; S.ho = R.m & 0xFFFFu; S.fl = fl;
}
static __device__ __forceinline__ h2 finalize(const ST& S, h2 up1, h2 up2,
                                              char* Pb, unsigned pr4, int lane) {
  const h2 one2 = {(_Float16)1.f, (_Float16)1.f};
  unsigned fl = S.fl;
  h2 b = S.braw;
  if (fl & 0x1Eu) {                           // hazard literal patches (uniform branch)
    unsigned mN1 = 0u-((fl>>1)&1u), mP1 = 0u-((fl>>2)&1u);
    unsigned mN2 = 0u-((fl>>3)&1u), mP2 = 0u-((fl>>4)&1u);
    b = hmax2(b, u2h(h2u(up1) & mN1));
    b = hmax2(b, u2h(h2u(one2 - up1) & mP1));
    b = hmax2(b, u2h(h2u(up2) & mN2));
    b = hmax2(b, u2h(h2u(one2 - up2) & mP2));
  }
  h2 prev;
  if (fl & 0x60u) prev = (fl & 0x20u) ? up1 : up2;   // head==head(c-1)/(c-2)
  else prev = S.prevraw;
  h2 upd;
  if (fl & 1u) upd = hmax2(prev, one2 - b);
  else         upd = hmin2(prev, b);
  if (lane < 4 && !(fl & 0x8000u))
    *(h2*)(Pb + S.ho + pr4) = upd;
  return upd;
}

__global__ __launch_bounds__(64, 2) void solve_kernel(
    const float* __restrict__ preds,
    const unsigned* __restrict__ ents,
    float* __restrict__ out) {
  __shared__ char Pb[LDSB];
  const int lane = threadIdx.x;
  const unsigned pr4 = (unsigned)(lane & 3) * 4u;    // row-pair byte offset
  const int g = lane >> 2;                           // literal group (16)
  const int bpa = ((lane ^ 32) << 2);                // bpermute addr for xor-32
  const int pr = lane & 3, cs = lane >> 2;
  const size_t row0 = (size_t)blockIdx.x * ROWS;

  if (lane < 4)      *(unsigned*)(Pb + ZOFF + lane*4) = 0u;
  else if (lane < 8) *(unsigned*)(Pb + OOFF + (lane-4)*4) = 0x3C003C00u;

  // stage in: [atom][8 rows] fp16; lane covers atoms (i*32+cs*2, +1), rows (2pr, 2pr+1)
  for (int i = 0; i < 16; ++i) {
    int a = i*32 + cs*2;
    float2 v0 = *(const float2*)(preds + (row0 + 2*pr)     * NUM + a);
    float2 v1 = *(const float2*)(preds + (row0 + 2*pr + 1) * NUM + a);
    h2 w0 = {(_Float16)v0.x, (_Float16)v1.x};
    h2 w1 = {(_Float16)v0.y, (_Float16)v1.y};
    *(h2*)(Pb + a*16 + pr*4) = w0;
    *(h2*)(Pb + (a+1)*16 + pr*4) = w1;
  }
  __syncthreads();

  auto ldq = [&](int c) { return *(const uint4*)(ents + (size_t)c * RSTR + g * 4); };
  auto ldm = [&](int c) { return ents[(size_t)c * RSTR + 64]; };   // uniform -> s_load

  uint4 Q2 = ldq(2), Q3 = ldq(3);
  unsigned M2 = ldm(2), M3 = ldm(3);
  RDv RA, RB; ST S0, S1;
  { uint4 Q0 = ldq(0); unsigned M0 = ldm(0); issue_reads(Q0, M0, Pb, pr4, RA); }
  { uint4 Q1 = ldq(1); unsigned M1 = ldm(1); issue_reads(Q1, M1, Pb, pr4, RB); }
  combine(RA, ents, 0, Pb, pr4, bpa, S0);
  h2 up1 = (h2)0.0f, up2 = (h2)0.0f;

  #pragma unroll 1
  for (int i = 0; i < CONS; i += 2) {
    issue_reads(Q2, M2, Pb, pr4, RA);                                  // reads(i+2)
    { h2 u = finalize(S0, up1, up2, Pb, pr4, lane); up2 = up1; up1 = u; }  // c=i
    combine(RB, ents, i+1, Pb, pr4, bpa, S1);
    Q2 = ldq(i+4); M2 = ldm(i+4);
    issue_reads(Q3, M3, Pb, pr4, RB);                                  // reads(i+3)
    { h2 u = finalize(S1, up1, up2, Pb, pr4, lane); up2 = up1; up1 = u; }  // c=i+1
    combine(RA, ents, i+2, Pb, pr4, bpa, S0);
    Q3 = ldq(i+5); M3 = ldm(i+5);
  }

  __syncthreads();
  for (int i = 0; i < 16; ++i) {
    int a = i*32 + cs*2;
    h2 w0 = *(const h2*)(Pb + a*16 + pr*4);
    h2 w1 = *(const h2*)(Pb + (a+1)*16 + pr*4);
    float2 v0 = {(float)w0.x, (float)w1.x};
    float2 v1 = {(float)w0.y, (float)w1.y};
    *(float2*)(out + (row0 + 2*pr)     * NUM + a) = v0;
    *(float2*)(out + (row0 + 2*pr + 1) * NUM + a) = v1;
  }
}

extern "C" void kernel_launch(void* const* d_in, const int* in_sizes, int n_in,
                              void* d_out, int out_size, void* d_ws, size_t ws_size,
                              hipStream_t stream) {
  (void)in_sizes; (void)n_in; (void)out_size; (void)ws_size;
  const float* preds     = (const float*)d_in[0];
  const float* pos       = (const float*)d_in[1];
  const float* neg       = (const float*)d_in[2];
  const int*   head_atom = (const int*)d_in[3];
  const int*   head_sign = (const int*)d_in[4];

  unsigned* ents = (unsigned*)d_ws;      // NPAD * RSTR * 4 ≈ 198 KB

  prep_kernel<<<NPAD, 64, 0, stream>>>(pos, neg, head_atom, head_sign, ents);
  solve_kernel<<<BATCH / ROWS, 64, 0, stream>>>(preds, ents, (float*)d_out);
}

// Round 10
// 278.852 us; speedup vs baseline: 1.1880x; 1.1880x over previous
//
#include <hip/hip_runtime.h>

#define BATCH 16384
#define NUM   512
#define CONS  512
#define ROWS  8                     // rows per wave/block
#define ZOFF  (NUM*16)              // zeros scratch (neg dummy), 8192
#define OOFF  (NUM*16 + 16)         // ones scratch (pos dummy), 8208
#define LDSB  (NUM*16 + 32)         // 8224 B
#define NPAD  (CONS + 4)
#define RSTR  96                    // record words per constraint (384 B, 16B-aligned quads)

typedef _Float16 h2 __attribute__((ext_vector_type(2)));
static __device__ __forceinline__ h2 u2h(unsigned u){ return __builtin_bit_cast(h2,u); }
static __device__ __forceinline__ unsigned h2u(h2 h){ return __builtin_bit_cast(unsigned,h); }
static __device__ __forceinline__ h2 hmax2(h2 a,h2 b){ return __builtin_elementwise_max(a,b); }
static __device__ __forceinline__ h2 hmin2(h2 a,h2 b){ return __builtin_elementwise_min(a,b); }
template<int C>
static __device__ __forceinline__ h2 rormax(h2 x) {
  unsigned v = (unsigned)__builtin_amdgcn_mov_dpp((int)h2u(x), C, 0xF, 0xF, true);
  return hmax2(x, u2h(v));
}

// record (RSTR words per c):
// [0..63] per-g quads at [g*4]: {N01, N23, P01, P23} packed u16 offset pairs
//   (quad word N01: lo = slotN[g], hi = slotN[16+g]; N23: lo = slotN[32+g], hi = slotN[48+g])
// [64] = ho | fl<<16 ; [65..72] exN ; [73..80] exP ; rest pad.
// fl: 0 sign |1 N1 |2 P1 |3 N2 |4 P2 |5 PR1 |6 PR2 |7-10 exN |11-14 exP |15 SKIP
__global__ __launch_bounds__(64) void prep_kernel(
    const float* __restrict__ pos, const float* __restrict__ neg,
    const int* __restrict__ head_atom, const int* __restrict__ head_sign,
    unsigned* __restrict__ ents) {
  int c = blockIdx.x, lane = threadIdx.x;
  unsigned* rec = ents + (size_t)c * RSTR;
  if (c >= CONS) {
    for (int t = lane; t < RSTR; t += 64) {
      unsigned v;
      if (t < 64) v = ((t & 3) < 2) ? 0x20002000u : 0x20102010u;
      else if (t == 64) v = (unsigned)ZOFF | (0x8000u << 16);   // SKIP
      else if (t < 73) v = ZOFF;
      else if (t < 81) v = OOFF;
      else v = 0;
      rec[t] = v;
    }
    return;
  }
  __shared__ unsigned short LN[96], LP[96];
  __shared__ unsigned short slotN[64], slotP[64];
  __shared__ unsigned char usedN[64], usedP[64];
  __shared__ unsigned short spill[16][8];
  __shared__ int spn[16];
  __shared__ unsigned short exN[8], exP[8];
  __shared__ int exn, exp_;
  slotN[lane] = ZOFF; slotP[lane] = OOFF;
  usedN[lane] = 0;    usedP[lane] = 0;
  if (lane < 8) { exN[lane] = ZOFF; exP[lane] = OOFF; }
  if (lane < 16) spn[lane] = 0;
  __syncthreads();

  int hp1 = (c >= 1) ? head_atom[c-1] : -1;
  int hp2 = (c >= 2) ? head_atom[c-2] : -1;
  int nN = 0, nP = 0;
  bool fN1=false, fP1=false, fN2=false, fP2=false;
  for (int k = 0; k < NUM/64; ++k) {
    int a = k*64 + lane;
    bool ln = neg[(size_t)c*NUM + a] != 0.f;
    bool lp = pos[(size_t)c*NUM + a] != 0.f;
    bool n1 = ln && (a == hp1), n2 = ln && (a == hp2);
    bool p1 = lp && (a == hp1), p2 = lp && (a == hp2);
    fN1 |= (__ballot(n1) != 0ull); fN2 |= (__ballot(n2) != 0ull);
    fP1 |= (__ballot(p1) != 0ull); fP2 |= (__ballot(p2) != 0ull);
    bool kn = ln && !n1 && !n2;
    bool kp = lp && !p1 && !p2;
    unsigned long long mn = __ballot(kn), mp = __ballot(kp);
    unsigned long long lt = (1ull << lane) - 1ull;
    int rn = nN + (int)__popcll(mn & lt);
    int rp = nP + (int)__popcll(mp & lt);
    if (kn && rn < 96) LN[rn] = (unsigned short)a;
    if (kp && rp < 96) LP[rp] = (unsigned short)a;
    nN += (int)__popcll(mn);
    nP += (int)__popcll(mp);
  }
  __syncthreads();
  // residue dealing: slot s = rr*8 + (a&7)  (spreads banks within each 16-slot step)
  if (lane < 16) {
    int r = lane & 7;
    bool isP = lane >= 8;
    const unsigned short* L = isP ? LP : LN;
    int n = isP ? nP : nN; if (n > 96) n = 96;
    unsigned short* slot = isP ? slotP : slotN;
    unsigned char* used = isP ? usedP : usedN;
    int rr = 0;
    for (int t = 0; t < n; ++t) {
      int a = L[t];
      if ((a & 7) == r) {
        if (rr < 8) { int s = rr*8 + r; slot[s] = (unsigned short)(a*16); used[s] = 1; }
        else if (rr < 16) spill[lane][rr-8] = (unsigned short)(a*16);
        ++rr;
      }
    }
    spn[lane] = rr > 8 ? (rr > 16 ? 8 : rr - 8) : 0;
  }
  __syncthreads();
  if (lane < 2) {                       // spill placement into free slots
    bool isP = lane == 1;
    unsigned short* slot = isP ? slotP : slotN;
    unsigned char* used = isP ? usedP : usedN;
    unsigned short* exb = isP ? exP : exN;
    int base = isP ? 8 : 0;
    int e = 0, scan = 0;
    for (int r = 0; r < 8; ++r) {
      int ns = spn[base + r];
      for (int k = 0; k < ns; ++k) {
        unsigned short v = spill[base + r][k];
        while (scan < 64 && used[scan]) ++scan;
        if (scan < 64) { slot[scan] = v; used[scan] = 1; }
        else if (e < 8) exb[e++] = v;
      }
    }
    if (isP) exp_ = e; else exn = e;
  }
  __syncthreads();

  int hc = head_atom[c];
  unsigned fl = 0;
  if (head_sign[c]) fl |= 1u;
  if (fN1) fl |= 2u;  if (fP1) fl |= 4u;
  if (fN2) fl |= 8u;  if (fP2) fl |= 16u;
  if (hc == hp1) fl |= 32u; else if (hc == hp2) fl |= 64u;
  fl |= ((unsigned)exn << 7) | ((unsigned)exp_ << 11);
  unsigned ho = (unsigned)hc * 16u;
  for (int t = lane; t < RSTR; t += 64) {
    unsigned v;
    if (t < 64) {
      int gg = t >> 2, q = t & 3;
      if (q == 0)      v = (unsigned)slotN[gg]    | ((unsigned)slotN[16+gg] << 16);
      else if (q == 1) v = (unsigned)slotN[32+gg] | ((unsigned)slotN[48+gg] << 16);
      else if (q == 2) v = (unsigned)slotP[gg]    | ((unsigned)slotP[16+gg] << 16);
      else             v = (unsigned)slotP[32+gg] | ((unsigned)slotP[48+gg] << 16);
    } else if (t == 64) v = ho | (fl << 16);
    else if (t < 73) v = exN[t - 65];
    else if (t < 81) v = exP[t - 73];
    else v = 0;
    rec[t] = v;
  }
}

struct RDv { h2 n0,n1,n2,n3,p0,p1,p2,p3,pv; unsigned m; };
struct ST  { h2 braw, prevraw; unsigned ho, fl; };

static __device__ __forceinline__ void issue_reads(uint4 q, unsigned m,
                                                   const char* Pb, unsigned pr4, RDv& R) {
  R.n0 = *(const h2*)(Pb + ((q.x & 0xFFFFu) + pr4));
  R.n1 = *(const h2*)(Pb + ((q.x >> 16)     + pr4));
  R.n2 = *(const h2*)(Pb + ((q.y & 0xFFFFu) + pr4));
  R.n3 = *(const h2*)(Pb + ((q.y >> 16)     + pr4));
  R.p0 = *(const h2*)(Pb + ((q.z & 0xFFFFu) + pr4));
  R.p1 = *(const h2*)(Pb + ((q.z >> 16)     + pr4));
  R.p2 = *(const h2*)(Pb + ((q.w & 0xFFFFu) + pr4));
  R.p3 = *(const h2*)(Pb + ((q.w >> 16)     + pr4));
  R.pv = *(const h2*)(Pb + ((m & 0xFFFFu) + pr4));
  R.m = m;
}
static __device__ __forceinline__ void combine(const RDv& R, const unsigned* ents,
                                               int c, const char* Pb, unsigned pr4, ST& S) {
  h2 aN = hmax2(hmax2(R.n0, R.n1), hmax2(R.n2, R.n3));
  h2 aP = hmin2(hmin2(R.p0, R.p1), hmin2(R.p2, R.p3));
  unsigned fl = ((unsigned)__builtin_amdgcn_readfirstlane((int)R.m)) >> 16;
  if (fl & 0x7F80u) {                        // rare extras tail (uniform)
    const unsigned* rec = ents + (size_t)c * RSTR;
    unsigned xn = (fl >> 7) & 15u, xp = (fl >> 11) & 15u;
    for (unsigned j = 0; j < xn; ++j) aN = hmax2(aN, *(const h2*)(Pb + (rec[65+j] + pr4)));
    for (unsigned j = 0; j < xp; ++j) aP = hmin2(aP, *(const h2*)(Pb + (rec[73+j] + pr4)));
  }
  const h2 one2 = {(_Float16)1.f, (_Float16)1.f};
  h2 bp = hmax2(aN, one2 - aP);               // >= 0 by construction
  bp = rormax<0x121>(bp);                     // row_ror:1  (16-lane row = fixed pr)
  bp = rormax<0x122>(bp);                     // row_ror:2
  bp = rormax<0x124>(bp);                     // row_ror:4
  bp = rormax<0x128>(bp);                     // row_ror:8  -> full row max, pure VALU
  S.braw = bp; S.prevraw = R.pv; S.ho = R.m & 0xFFFFu; S.fl = fl;
}
static __device__ __forceinline__ h2 finalize(const ST& S, h2 up1, h2 up2,
                                              char* Pb, unsigned pr4, int lane) {
  const h2 one2 = {(_Float16)1.f, (_Float16)1.f};
  unsigned fl = S.fl;
  h2 b = S.braw;
  if (fl & 0x1Eu) {                           // hazard literal patches (uniform branch)
    unsigned mN1 = 0u-((fl>>1)&1u), mP1 = 0u-((fl>>2)&1u);
    unsigned mN2 = 0u-((fl>>3)&1u), mP2 = 0u-((fl>>4)&1u);
    b = hmax2(b, u2h(h2u(up1) & mN1));
    b = hmax2(b, u2h(h2u(one2 - up1) & mP1));
    b = hmax2(b, u2h(h2u(up2) & mN2));
    b = hmax2(b, u2h(h2u(one2 - up2) & mP2));
  }
  h2 prev;
  if (fl & 0x60u) prev = (fl & 0x20u) ? up1 : up2;   // head==head(c-1)/(c-2)
  else prev = S.prevraw;
  h2 upd;
  if (fl & 1u) upd = hmax2(prev, one2 - b);
  else         upd = hmin2(prev, b);
  if ((lane & 15) == 0 && !(fl & 0x8000u))
    *(h2*)(Pb + S.ho + pr4) = upd;
  return upd;
}

__global__ __launch_bounds__(64, 2) void solve_kernel(
    const float* __restrict__ preds,
    const unsigned* __restrict__ ents,
    float* __restrict__ out) {
  __shared__ char Pb[LDSB];
  const int lane = threadIdx.x;
  const unsigned pr4 = (unsigned)(lane >> 4) * 4u;   // row-pair byte offset (pr = DPP row)
  const int g = lane & 15;                           // literal group within row
  const int r2 = lane >> 4, cs = lane & 15;
  const size_t row0 = (size_t)blockIdx.x * ROWS;

  if (lane < 4)      *(unsigned*)(Pb + ZOFF + lane*4) = 0u;
  else if (lane < 8) *(unsigned*)(Pb + OOFF + (lane-4)*4) = 0x3C003C00u;

  // stage in: [atom][8 rows] fp16
  for (int i = 0; i < 16; ++i) {
    int a = i*32 + cs*2;
    float2 v0 = *(const float2*)(preds + (row0 + 2*r2)     * NUM + a);
    float2 v1 = *(const float2*)(preds + (row0 + 2*r2 + 1) * NUM + a);
    h2 w0 = {(_Float16)v0.x, (_Float16)v1.x};
    h2 w1 = {(_Float16)v0.y, (_Float16)v1.y};
    *(h2*)(Pb + a*16 + r2*4) = w0;
    *(h2*)(Pb + (a+1)*16 + r2*4) = w1;
  }
  __syncthreads();

  auto ldq = [&](int c) { return *(const uint4*)(ents + (size_t)c * RSTR + g * 4); };
  auto ldm = [&](int c) { return ents[(size_t)c * RSTR + 64]; };   // uniform -> scalar

  uint4 Q2 = ldq(2), Q3 = ldq(3);
  unsigned M2 = ldm(2), M3 = ldm(3);
  RDv RA, RB; ST S0, S1;
  { uint4 Q0 = ldq(0); unsigned M0 = ldm(0); issue_reads(Q0, M0, Pb, pr4, RA); }
  { uint4 Q1 = ldq(1); unsigned M1 = ldm(1); issue_reads(Q1, M1, Pb, pr4, RB); }
  combine(RA, ents, 0, Pb, pr4, S0);
  h2 up1 = (h2)0.0f, up2 = (h2)0.0f;

  #pragma unroll 1
  for (int i = 0; i < CONS; i += 2) {
    issue_reads(Q2, M2, Pb, pr4, RA);                                  // reads(i+2)
    { h2 u = finalize(S0, up1, up2, Pb, pr4, lane); up2 = up1; up1 = u; }  // c=i
    combine(RB, ents, i+1, Pb, pr4, S1);
    Q2 = ldq(i+4); M2 = ldm(i+4);
    issue_reads(Q3, M3, Pb, pr4, RB);                                  // reads(i+3)
    { h2 u = finalize(S1, up1, up2, Pb, pr4, lane); up2 = up1; up1 = u; }  // c=i+1
    combine(RA, ents, i+2, Pb, pr4, S0);
    Q3 = ldq(i+5); M3 = ldm(i+5);
  }

  __syncthreads();
  for (int i = 0; i < 16; ++i) {
    int a = i*32 + cs*2;
    h2 w0 = *(const h2*)(Pb + a*16 + r2*4);
    h2 w1 = *(const h2*)(Pb + (a+1)*16 + r2*4);
    float2 v0 = {(float)w0.x, (float)w1.x};
    float2 v1 = {(float)w0.y, (float)w1.y};
    *(float2*)(out + (row0 + 2*r2)     * NUM + a) = v0;
    *(float2*)(out + (row0 + 2*r2 + 1) * NUM + a) = v1;
  }
}

extern "C" void kernel_launch(void* const* d_in, const int* in_sizes, int n_in,
                              void* d_out, int out_size, void* d_ws, size_t ws_size,
                              hipStream_t stream) {
  (void)in_sizes; (void)n_in; (void)out_size; (void)ws_size;
  const float* preds     = (const float*)d_in[0];
  const float* pos       = (const float*)d_in[1];
  const float* neg       = (const float*)d_in[2];
  const int*   head_atom = (const int*)d_in[3];
  const int*   head_sign = (const int*)d_in[4];

  unsigned* ents = (unsigned*)d_ws;      // NPAD * RSTR * 4 ≈ 198 KB

  prep_kernel<<<NPAD, 64, 0, stream>>>(pos, neg, head_atom, head_sign, ents);
  solve_kernel<<<BATCH / ROWS, 64, 0, stream>>>(preds, ents, (float*)d_out);
}